// Round 3
// baseline (6401.147 us; speedup 1.0000x reference)
//
#include <hip/hip_runtime.h>
#include <hip/hip_cooperative_groups.h>

namespace cg = cooperative_groups;

#define NSEQ 32768
#define NB 8
#define NC 16
#define CHUNK 512
#define NBLK 512          // NB * NSEQ / CHUNK
#define NTHR 256

__device__ __forceinline__ float sigm_f(float x) {
    return __fdividef(1.f, 1.f + __expf(-x));
}
__device__ __forceinline__ float tanh_f(float x) {
    return __fdividef(2.f, 1.f + __expf(-2.f * x)) - 1.f;
}

// hG layout: [2 parity][NBLK][NC][CHUNK] fp32 (32 MiB in d_ws).
// Parity p holds layer tails published for the next layer; parity 1 finally
// holds h_final for the head kernel.
__global__ __launch_bounds__(NTHR, 2) void k_stack(
    const float* __restrict__ x,
    const float* __restrict__ w0, const float* __restrict__ b0,
    const float* __restrict__ wf, const float* __restrict__ bf,
    const float* __restrict__ wg, const float* __restrict__ bg,
    float* __restrict__ hG)
{
    __shared__ float hs[2][NC][CHUNK];   // 64 KiB: double-buffered h chunk
    cg::grid_group grid = cg::this_grid();
    const int b = blockIdx.x;
    const int t = threadIdx.x;
    const int chunki = b & 63;
    const int batch = b >> 6;
    const float* xb = x + (size_t)batch * NSEQ + chunki * CHUNK;
    const float inv = 1.f / 32768.f;

    // ---- layer 0: EXACT round-1 k_layer0 math (op order preserved) --------
#pragma unroll 1
    for (int pp = 0; pp < 2; ++pp) {
        int p = t + pp * NTHR;
        float xc = xb[p] * inv;
        float xp = (p > 0 || chunki > 0) ? xb[p - 1] * inv : 0.f;
#pragma unroll
        for (int c = 0; c < NC; c++) {
            float o = w0[c * 2] * xp + w0[c * 2 + 1] * xc + b0[c];
            hs[0][c][p] = xc + o;
        }
    }
    // publish tail for layer 1 (d=2) into parity 0
    {
        float* dst = hG + ((size_t)b) * NC * CHUNK;   // parity 0
#pragma unroll 1
        for (int pp = 0; pp < 2; ++pp) {
            int p = t + pp * NTHR;
            if (p >= CHUNK - 2) {
#pragma unroll
                for (int c = 0; c < NC; c++) dst[c * CHUNK + p] = hs[0][c][p];
            }
        }
    }
    __threadfence();
    grid.sync();

    int cur = 0, par = 0;
#pragma unroll 1
    for (int i = 1; i <= 29; ++i) {
        const int d = 1 << (i % 10);
        const float* wfl = wf + (size_t)(i - 1) * NC * NC * 2;
        const float* wgl = wg + (size_t)(i - 1) * NC * NC * 2;
        const float* bfl = bf + (size_t)(i - 1) * NC;
        const float* bgl = bg + (size_t)(i - 1) * NC;
        const float* hbL = hG + ((size_t)par * NBLK + (b - 1)) * NC * CHUNK;
        const int nxt = cur ^ 1;

        // serialize the two positions: halves peak live VGPRs, keeps
        // per-position op order EXACTLY as round-1 k_layer
#pragma unroll 1
        for (int pp = 0; pp < 2; ++pp) {
            const int p = t + pp * NTHR;
            float hc[NC], hp[NC];
#pragma unroll
            for (int c = 0; c < NC; c++) hc[c] = hs[cur][c][p];
            if (p >= d) {
#pragma unroll
                for (int c = 0; c < NC; c++) hp[c] = hs[cur][c][p - d];
            } else if (chunki > 0) {
#pragma unroll
                for (int c = 0; c < NC; c++) hp[c] = hbL[c * CHUNK + (CHUNK - d + p)];
            } else {
#pragma unroll
                for (int c = 0; c < NC; c++) hp[c] = 0.f;
            }

            float f[NC], g[NC];
#pragma unroll
            for (int co = 0; co < NC; co++) { f[co] = bfl[co]; g[co] = bgl[co]; }

#pragma unroll
            for (int ci = 0; ci < NC; ci++) {
                float xp = hp[ci], xc = hc[ci];
#pragma unroll
                for (int co = 0; co < NC; co++) {
                    f[co] = fmaf(wfl[(co * NC + ci) * 2 + 0], xp, f[co]);
                    f[co] = fmaf(wfl[(co * NC + ci) * 2 + 1], xc, f[co]);
                    g[co] = fmaf(wgl[(co * NC + ci) * 2 + 0], xp, g[co]);
                    g[co] = fmaf(wgl[(co * NC + ci) * 2 + 1], xc, g[co]);
                }
            }

#pragma unroll
            for (int co = 0; co < NC; co++) {
                float outv = tanh_f(f[co]) * sigm_f(g[co]);
                hs[nxt][co][p] = hc[co] + outv;
            }
        }

        if (i < 29) {
            const int dt = 1 << ((i + 1) % 10);
            float* dst = hG + ((size_t)(par ^ 1) * NBLK + b) * NC * CHUNK;
#pragma unroll 1
            for (int pp = 0; pp < 2; ++pp) {
                int p = t + pp * NTHR;
                if (p >= CHUNK - dt) {
#pragma unroll
                    for (int c = 0; c < NC; c++) dst[c * CHUNK + p] = hs[nxt][c][p];
                }
            }
            __threadfence();
            grid.sync();
        }
        cur ^= 1; par ^= 1;
    }

    // ---- write raw h_final to parity-1 buffer for the head -----------------
    {
        float* dst = hG + ((size_t)NBLK + b) * NC * CHUNK;   // parity 1
#pragma unroll 1
        for (int pp = 0; pp < 2; ++pp) {
            int p = t + pp * NTHR;
#pragma unroll
            for (int c = 0; c < NC; c++)
                dst[c * CHUNK + p] = hs[cur][c][p];
        }
    }
}

// Head: EXACT round-1 math. r = relu(h - xin); a = relu(wa@r+ba);
// o = wo@relu(a)+bo; log_softmax; mask. 64 positions per block.
// h layout here: [NBLK][NC][CHUNK]
__global__ __launch_bounds__(256) void k_final(
    const float* __restrict__ hbuf, const float* __restrict__ x,
    const int* __restrict__ lengths,
    const float* __restrict__ wa, const float* __restrict__ ba,
    const float* __restrict__ wo, const float* __restrict__ bo,
    float* __restrict__ out)
{
    __shared__ float s_r[64][17];
    __shared__ float s_ra[64][65];
    __shared__ float s_red[2][4][64];

    int t = threadIdx.x;
    int p = t & 63;
    int q = __builtin_amdgcn_readfirstlane(t >> 6);
    int blk = blockIdx.x;
    int batch = blk >> 9;
    int tile = blk & 511;
    int cb = batch * 64 + (tile >> 3);      // chunk index into hbuf
    int off = (tile & 7) * 64;              // position offset within chunk
    int n = tile * 64 + p;                  // position within sequence
    size_t pos = (size_t)batch * NSEQ + n;
    float xin = x[pos] * (1.f / 32768.f);

    // phase 1: stage relu(h - xin), same subtract/fmax per element as round 1
    {
        const float* rb = hbuf + (size_t)cb * NC * CHUNK + off;
#pragma unroll
        for (int cc = 0; cc < 4; ++cc) {
            int c = q * 4 + cc;
            s_r[p][c] = fmaxf(rb[(size_t)c * CHUNK + p] - xin, 0.f);
        }
    }
    __syncthreads();

    // phase 2: a[j] for j = q*16 .. q*16+15
    {
        float rr[NC];
#pragma unroll
        for (int c = 0; c < NC; c++) rr[c] = s_r[p][c];
#pragma unroll
        for (int jj = 0; jj < 16; jj++) {
            int j = q * 16 + jj;
            float acc = ba[j];
#pragma unroll
            for (int c = 0; c < NC; c++) acc = fmaf(wa[j * NC + c], rr[c], acc);
            s_ra[p][j] = fmaxf(acc, 0.f);
        }
    }
    __syncthreads();

    // phase 3: o[k] for k = q*64 .. q*64+63, logsumexp across block
    float ra[64];
#pragma unroll
    for (int j = 0; j < 64; j++) ra[j] = s_ra[p][j];

    float o[64];
    float m = -1e30f;
#pragma unroll 8
    for (int kk = 0; kk < 64; kk++) {
        int k = q * 64 + kk;
        float acc = bo[k];
#pragma unroll
        for (int j = 0; j < 64; j++) acc = fmaf(wo[k * 64 + j], ra[j], acc);
        o[kk] = acc;
        m = fmaxf(m, acc);
    }
    s_red[0][q][p] = m;
    __syncthreads();
    m = fmaxf(fmaxf(s_red[0][0][p], s_red[0][1][p]),
              fmaxf(s_red[0][2][p], s_red[0][3][p]));
    float s = 0.f;
#pragma unroll
    for (int kk = 0; kk < 64; kk++) s += __expf(o[kk] - m);
    s_red[1][q][p] = s;
    __syncthreads();
    s = s_red[1][0][p] + s_red[1][1][p] + s_red[1][2][p] + s_red[1][3][p];
    float lse = m + __logf(s);

    bool valid = n < lengths[batch];
    float* po = out + ((size_t)batch * 256 + q * 64) * NSEQ + n;
#pragma unroll
    for (int kk = 0; kk < 64; kk++) {
        float v = valid ? (o[kk] - lse) : 0.f;
        __builtin_nontemporal_store(v, &po[(size_t)kk * NSEQ]);
    }
}

extern "C" void kernel_launch(void* const* d_in, const int* in_sizes, int n_in,
                              void* d_out, int out_size, void* d_ws, size_t ws_size,
                              hipStream_t stream) {
    const float* x   = (const float*)d_in[0];
    const int* lens  = (const int*)d_in[1];
    const float* w0  = (const float*)d_in[2];
    const float* b0  = (const float*)d_in[3];
    const float* wf  = (const float*)d_in[4];
    const float* bf  = (const float*)d_in[5];
    const float* wg  = (const float*)d_in[6];
    const float* bg  = (const float*)d_in[7];
    const float* wa  = (const float*)d_in[8];
    const float* ba  = (const float*)d_in[9];
    const float* wo  = (const float*)d_in[10];
    const float* bo  = (const float*)d_in[11];
    float* out = (float*)d_out;

    float* hG = (float*)d_ws;   // [2][NBLK][NC][CHUNK] = 32 MiB

    void* args[] = {
        (void*)&x, (void*)&w0, (void*)&b0, (void*)&wf, (void*)&bf,
        (void*)&wg, (void*)&bg, (void*)&hG
    };
    hipLaunchCooperativeKernel((const void*)k_stack, dim3(NBLK), dim3(NTHR),
                               args, 0, stream);

    const float* hbuf = hG + (size_t)NBLK * NC * CHUNK;   // parity-1 buffer
    k_final<<<dim3(NB * (NSEQ / 64)), dim3(256), 0, stream>>>(
        hbuf, x, lens, wa, ba, wo, bo, out);
}

// Round 4
// 1337.770 us; speedup vs baseline: 4.7849x; 4.7849x over previous
//
#include <hip/hip_runtime.h>

#define NSEQ 32768
#define NB 8
#define NC 16
#define CHUNK 512
#define NBLK 512          // NB * NSEQ / CHUNK
#define NTHR 256
#define NLAY 29           // gated layers 1..29

__device__ __forceinline__ float sigm_f(float x) {
    return __fdividef(1.f, 1.f + __expf(-x));
}
__device__ __forceinline__ float tanh_f(float x) {
    return __fdividef(2.f, 1.f + __expf(-2.f * x)) - 1.f;
}

// Cross-XCD-coherent accesses: agent-scope relaxed atomics bypass the
// non-coherent per-XCD L2 (no buffer_wbl2/inv cache maintenance emitted).
__device__ __forceinline__ void st_agent(float* p, float v) {
    __hip_atomic_store(p, v, __ATOMIC_RELAXED, __HIP_MEMORY_SCOPE_AGENT);
}
__device__ __forceinline__ float ld_agent(const float* p) {
    return __hip_atomic_load((float*)p, __ATOMIC_RELAXED, __HIP_MEMORY_SCOPE_AGENT);
}
__device__ __forceinline__ void flag_set(unsigned* p) {
    __hip_atomic_store(p, 1u, __ATOMIC_RELAXED, __HIP_MEMORY_SCOPE_AGENT);
}
__device__ __forceinline__ void flag_wait(unsigned* p) {
    while (__hip_atomic_load(p, __ATOMIC_RELAXED, __HIP_MEMORY_SCOPE_AGENT) == 0u)
        __builtin_amdgcn_s_sleep(2);
}

// hG: [2 parity][NBLK][NC][CHUNK] tail-exchange buffers (32 MiB)
// hF: [NBLK][NC][CHUNK] final h for the head (16 MiB)
// fready[i][b]: block b's layer-i output tail is visible (i = 0..28)
// fack[i][b]:   block b's layer-i tail was consumed by block b+1
__global__ __launch_bounds__(NTHR, 2) void k_stack(
    const float* __restrict__ x,
    const float* __restrict__ w0, const float* __restrict__ b0,
    const float* __restrict__ wf, const float* __restrict__ bf,
    const float* __restrict__ wg, const float* __restrict__ bg,
    float* __restrict__ hG, float* __restrict__ hF,
    unsigned* __restrict__ fready, unsigned* __restrict__ fack)
{
    __shared__ float hs[2][NC][CHUNK];   // 64 KiB double-buffered h chunk
    const int b = blockIdx.x;
    const int t = threadIdx.x;
    const int chunki = b & 63;
    const int batch = b >> 6;
    const bool havL = (chunki > 0);
    const bool havR = (chunki < 63);
    const float* xb = x + (size_t)batch * NSEQ + chunki * CHUNK;
    const float inv = 1.f / 32768.f;

    // ---- layer 0: frozen round-1 math --------------------------------------
#pragma unroll 1
    for (int pp = 0; pp < 2; ++pp) {
        int p = t + pp * NTHR;
        float xc = xb[p] * inv;
        float xp = (p > 0 || chunki > 0) ? xb[p - 1] * inv : 0.f;
#pragma unroll
        for (int c = 0; c < NC; c++) {
            float o = w0[c * 2] * xp + w0[c * 2 + 1] * xc + b0[c];
            hs[0][c][p] = xc + o;
        }
    }
    if (havR) {   // publish tail for layer 1 (d=2) into parity 0
        float* dst = hG + ((size_t)b) * NC * CHUNK;
#pragma unroll 1
        for (int pp = 0; pp < 2; ++pp) {
            int p = t + pp * NTHR;
            if (p >= CHUNK - 2) {
#pragma unroll
                for (int c = 0; c < NC; c++)
                    st_agent(&dst[c * CHUNK + p], hs[0][c][p]);
            }
        }
    }
    __syncthreads();   // drains vmcnt: tail stores globally visible
    if (t == 0) {
        if (havR) flag_set(&fready[0 * NBLK + b]);
        if (havL) flag_wait(&fready[0 * NBLK + (b - 1)]);
    }
    __syncthreads();

    int cur = 0, par = 0;
#pragma unroll 1
    for (int i = 1; i <= NLAY; ++i) {
        const int d = 1 << (i % 10);
        const float* wfl = wf + (size_t)(i - 1) * NC * NC * 2;
        const float* wgl = wg + (size_t)(i - 1) * NC * NC * 2;
        const float* bfl = bf + (size_t)(i - 1) * NC;
        const float* bgl = bg + (size_t)(i - 1) * NC;
        const float* hbL = hG + ((size_t)par * NBLK + (b - 1)) * NC * CHUNK;
        const int nxt = cur ^ 1;
        const int dt = (i < NLAY) ? (1 << ((i + 1) % 10)) : 0;
        float* dst = hG + ((size_t)(par ^ 1) * NBLK + b) * NC * CHUNK;
        const bool pub = (i < NLAY) && havR;

#pragma unroll 1
        for (int pp = 0; pp < 2; ++pp) {
            const int p = t + pp * NTHR;
            float hc[NC], hp[NC];
#pragma unroll
            for (int c = 0; c < NC; c++) hc[c] = hs[cur][c][p];
            if (p >= d) {
#pragma unroll
                for (int c = 0; c < NC; c++) hp[c] = hs[cur][c][p - d];
            } else if (havL) {
#pragma unroll
                for (int c = 0; c < NC; c++)
                    hp[c] = ld_agent(&hbL[c * CHUNK + (CHUNK - d + p)]);
            } else {
#pragma unroll
                for (int c = 0; c < NC; c++) hp[c] = 0.f;
            }

            float f[NC], g[NC];
#pragma unroll
            for (int co = 0; co < NC; co++) { f[co] = bfl[co]; g[co] = bgl[co]; }

#pragma unroll
            for (int ci = 0; ci < NC; ci++) {
                float xp = hp[ci], xc = hc[ci];
#pragma unroll
                for (int co = 0; co < NC; co++) {
                    f[co] = fmaf(wfl[(co * NC + ci) * 2 + 0], xp, f[co]);
                    f[co] = fmaf(wfl[(co * NC + ci) * 2 + 1], xc, f[co]);
                    g[co] = fmaf(wgl[(co * NC + ci) * 2 + 0], xp, g[co]);
                    g[co] = fmaf(wgl[(co * NC + ci) * 2 + 1], xc, g[co]);
                }
            }

#pragma unroll
            for (int co = 0; co < NC; co++) {
                float outv = tanh_f(f[co]) * sigm_f(g[co]);
                float hv = hc[co] + outv;
                hs[nxt][co][p] = hv;
                if (pub && p >= CHUNK - dt)
                    st_agent(&dst[co * CHUNK + p], hv);
            }
        }

        __syncthreads();   // hs[nxt] done; tail stores drained; hbL reads done
        if (t == 0) {
            // SET before WAIT (deadlock-freedom)
            if (pub)  flag_set(&fready[i * NBLK + b]);
            if (havL) flag_set(&fack[(i - 1) * NBLK + (b - 1)]);   // consumed left layer-(i-1) tail
            if (i < NLAY && havL) flag_wait(&fready[i * NBLK + (b - 1)]);
            // layer i+1 publish reuses layer (i-1)'s parity slot: need right ack
            if (i + 1 < NLAY && havR) flag_wait(&fack[(i - 1) * NBLK + b]);
        }
        __syncthreads();
        cur ^= 1; par ^= 1;
    }

    // ---- write h_final to hF (plain stores; kernel boundary synchronizes) --
    {
        float* dst = hF + (size_t)b * NC * CHUNK;
#pragma unroll 1
        for (int pp = 0; pp < 2; ++pp) {
            int p = t + pp * NTHR;
#pragma unroll
            for (int c = 0; c < NC; c++)
                dst[c * CHUNK + p] = hs[cur][c][p];
        }
    }
}

// Head: frozen round-1 math. r = relu(h - xin); a = relu(wa@r+ba);
// o = wo@a+bo; log_softmax; mask. 64 positions per block.
__global__ __launch_bounds__(256) void k_final(
    const float* __restrict__ hbuf, const float* __restrict__ x,
    const int* __restrict__ lengths,
    const float* __restrict__ wa, const float* __restrict__ ba,
    const float* __restrict__ wo, const float* __restrict__ bo,
    float* __restrict__ out)
{
    __shared__ float s_r[64][17];
    __shared__ float s_ra[64][65];
    __shared__ float s_red[2][4][64];

    int t = threadIdx.x;
    int p = t & 63;
    int q = __builtin_amdgcn_readfirstlane(t >> 6);
    int blk = blockIdx.x;
    int batch = blk >> 9;
    int tile = blk & 511;
    int cb = batch * 64 + (tile >> 3);
    int off = (tile & 7) * 64;
    int n = tile * 64 + p;
    size_t pos = (size_t)batch * NSEQ + n;
    float xin = x[pos] * (1.f / 32768.f);

    {
        const float* rb = hbuf + (size_t)cb * NC * CHUNK + off;
#pragma unroll
        for (int cc = 0; cc < 4; ++cc) {
            int c = q * 4 + cc;
            s_r[p][c] = fmaxf(rb[(size_t)c * CHUNK + p] - xin, 0.f);
        }
    }
    __syncthreads();

    {
        float rr[NC];
#pragma unroll
        for (int c = 0; c < NC; c++) rr[c] = s_r[p][c];
#pragma unroll
        for (int jj = 0; jj < 16; jj++) {
            int j = q * 16 + jj;
            float acc = ba[j];
#pragma unroll
            for (int c = 0; c < NC; c++) acc = fmaf(wa[j * NC + c], rr[c], acc);
            s_ra[p][j] = fmaxf(acc, 0.f);
        }
    }
    __syncthreads();

    float ra[64];
#pragma unroll
    for (int j = 0; j < 64; j++) ra[j] = s_ra[p][j];

    float o[64];
    float m = -1e30f;
#pragma unroll 8
    for (int kk = 0; kk < 64; kk++) {
        int k = q * 64 + kk;
        float acc = bo[k];
#pragma unroll
        for (int j = 0; j < 64; j++) acc = fmaf(wo[k * 64 + j], ra[j], acc);
        o[kk] = acc;
        m = fmaxf(m, acc);
    }
    s_red[0][q][p] = m;
    __syncthreads();
    m = fmaxf(fmaxf(s_red[0][0][p], s_red[0][1][p]),
              fmaxf(s_red[0][2][p], s_red[0][3][p]));
    float s = 0.f;
#pragma unroll
    for (int kk = 0; kk < 64; kk++) s += __expf(o[kk] - m);
    s_red[1][q][p] = s;
    __syncthreads();
    s = s_red[1][0][p] + s_red[1][1][p] + s_red[1][2][p] + s_red[1][3][p];
    float lse = m + __logf(s);

    bool valid = n < lengths[batch];
    float* po = out + ((size_t)batch * 256 + q * 64) * NSEQ + n;
#pragma unroll
    for (int kk = 0; kk < 64; kk++) {
        float v = valid ? (o[kk] - lse) : 0.f;
        __builtin_nontemporal_store(v, &po[(size_t)kk * NSEQ]);
    }
}

extern "C" void kernel_launch(void* const* d_in, const int* in_sizes, int n_in,
                              void* d_out, int out_size, void* d_ws, size_t ws_size,
                              hipStream_t stream) {
    const float* x   = (const float*)d_in[0];
    const int* lens  = (const int*)d_in[1];
    const float* w0  = (const float*)d_in[2];
    const float* b0  = (const float*)d_in[3];
    const float* wf  = (const float*)d_in[4];
    const float* bf  = (const float*)d_in[5];
    const float* wg  = (const float*)d_in[6];
    const float* bg  = (const float*)d_in[7];
    const float* wa  = (const float*)d_in[8];
    const float* ba  = (const float*)d_in[9];
    const float* wo  = (const float*)d_in[10];
    const float* bo  = (const float*)d_in[11];
    float* out = (float*)d_out;

    float* hG = (float*)d_ws;                               // 32 MiB
    float* hF = hG + (size_t)2 * NBLK * NC * CHUNK;         // 16 MiB
    unsigned* fready = (unsigned*)(hF + (size_t)NBLK * NC * CHUNK);
    unsigned* fack   = fready + NLAY * NBLK;

    // reset flags each launch (stream-ordered, graph-capturable)
    hipMemsetAsync(fready, 0, (size_t)2 * NLAY * NBLK * sizeof(unsigned), stream);

    void* args[] = {
        (void*)&x, (void*)&w0, (void*)&b0, (void*)&wf, (void*)&bf,
        (void*)&wg, (void*)&bg, (void*)&hG, (void*)&hF,
        (void*)&fready, (void*)&fack
    };
    hipLaunchCooperativeKernel((const void*)k_stack, dim3(NBLK), dim3(NTHR),
                               args, 0, stream);

    k_final<<<dim3(NB * (NSEQ / 64)), dim3(256), 0, stream>>>(
        hF, x, lens, wa, ba, wo, bo, out);
}